// Round 4
// baseline (837.216 us; speedup 1.0000x reference)
//
#include <hip/hip_runtime.h>

typedef unsigned short u16;
typedef __bf16 bf16x8 __attribute__((ext_vector_type(8)));
typedef float f32x4 __attribute__((ext_vector_type(4)));

// Problem constants: B=8, N=2048, DH=512
#define SEQN 2048
#define DHID 512

static __device__ __forceinline__ float bf2f(u16 u) {
    union { unsigned int i; float f; } c; c.i = ((unsigned int)u) << 16; return c.f;
}
static __device__ __forceinline__ u16 f2bf(float f) {
    union { float f; unsigned int i; } c; c.f = f;
    unsigned int x = c.i;
    return (u16)((x + 0x7fffu + ((x >> 16) & 1u)) >> 16);
}

// async global->LDS, 16B per lane, LDS dest = wave-uniform base + lane*16
static __device__ __forceinline__ void gld_lds16(const u16* g, u16* l) {
    __builtin_amdgcn_global_load_lds(
        (__attribute__((address_space(1))) void*)(g),
        (__attribute__((address_space(3))) void*)(l), 16, 0, 0);
}

// ---------------------------------------------------------------------------
// fp32 -> bf16 conversion (n multiple of 8)
// ---------------------------------------------------------------------------
__global__ __launch_bounds__(256) void cvt_kernel(const float* __restrict__ src,
                                                  u16* __restrict__ dst, int n) {
    int i = (blockIdx.x * 256 + threadIdx.x) * 8;
    if (i >= n) return;
    float4 a = *(const float4*)(src + i);
    float4 b = *(const float4*)(src + i + 4);
    union { uint4 u; u16 s[8]; } o;
    o.s[0] = f2bf(a.x); o.s[1] = f2bf(a.y); o.s[2] = f2bf(a.z); o.s[3] = f2bf(a.w);
    o.s[4] = f2bf(b.x); o.s[5] = f2bf(b.y); o.s[6] = f2bf(b.z); o.s[7] = f2bf(b.w);
    *(uint4*)(dst + i) = o.u;
}

// fp32 [K][N] -> bf16 transposed [N][K]
__global__ __launch_bounds__(256) void cvt_t_kernel(const float* __restrict__ src,
                                                    u16* __restrict__ dst, int K, int N) {
    int idx = blockIdx.x * 256 + threadIdx.x;
    if (idx >= K * N) return;
    int n = idx / K, k = idx - n * K;
    dst[idx] = f2bf(src[(size_t)k * N + n]);
}

// ---------------------------------------------------------------------------
// hop_emb row means (fp32 in): hm[j] = mean_d hop_emb[j][d]
// ---------------------------------------------------------------------------
__global__ void hmean_kernel(const float* __restrict__ hop, float* __restrict__ hm) {
    int j = blockIdx.x, t = threadIdx.x;           // 64 threads
    const float* p = hop + (size_t)j * DHID + t * 8;
    float4 a = *(const float4*)p;
    float4 b = *(const float4*)(p + 4);
    float s = a.x + a.y + a.z + a.w + b.x + b.y + b.z + b.w;
#pragma unroll
    for (int m = 1; m < 64; m <<= 1) s += __shfl_xor(s, m);
    if (t == 0) hm[j] = s * (1.0f / (float)DHID);
}

// ---------------------------------------------------------------------------
// BT MFMA GEMM: C[M,N] = A[M,K] * Bt[N,K]^T + epilogue  (A,Bt,C bf16)
// Tile 128x128x32, 256 threads (4 waves as 2x2 of 64x64), 16x16x32 MFMA.
// EPI_QKV: N=1536 concat [Q|K|Vt]; sel = gn>>9 is block-uniform.
// ---------------------------------------------------------------------------
enum { EPI_BIAS = 0, EPI_RELU = 1, EPI_PLAIN = 3, EPI_BIAS_T = 4, EPI_QKV = 5 };

template <int EPI>
__global__ __launch_bounds__(256) void gemm_bt(
    const u16* __restrict__ A, const u16* __restrict__ Bt, u16* __restrict__ C,
    const float* __restrict__ bias,
    int K, int lda, int ldb, int ldc,
    u16* __restrict__ Qo, u16* __restrict__ Ko, u16* __restrict__ Vto,
    const float* __restrict__ bq_, const float* __restrict__ bk_,
    const float* __restrict__ bv_)
{
    __shared__ u16 As[128 * 32];   // 8 KB, [row][k], row stride 64 B
    __shared__ u16 Bs[128 * 32];   // 8 KB, [n][k]

    const int tid = threadIdx.x;
    const u16* Ab = A;
    const u16* Bb = Bt;

    const int bm0 = blockIdx.y * 128, bn0 = blockIdx.x * 128;
    const int wid = tid >> 6, lane = tid & 63, quad = lane >> 4, l16 = lane & 15;
    const int wm = (wid >> 1) * 64, wn = (wid & 1) * 64;
    const int srow = lane >> 2;            // 0..15: row within 16-row chunk
    const int skof = (lane & 3) * 8;       // k element offset (8 bf16 = 16 B)

    f32x4 acc[4][4];
#pragma unroll
    for (int i = 0; i < 4; ++i)
#pragma unroll
        for (int j = 0; j < 4; ++j) acc[i][j] = (f32x4){0.f, 0.f, 0.f, 0.f};

    for (int k0 = 0; k0 < K; k0 += 32) {
#pragma unroll
        for (int it = 0; it < 2; ++it) {
            int c = wid * 2 + it;          // wave-uniform
            gld_lds16(Ab + (size_t)(bm0 + c * 16 + srow) * lda + k0 + skof,
                      &As[c * 512]);
        }
#pragma unroll
        for (int it = 0; it < 2; ++it) {
            int c = wid * 2 + it;
            gld_lds16(Bb + (size_t)(bn0 + c * 16 + srow) * ldb + k0 + skof,
                      &Bs[c * 512]);
        }
        __syncthreads();

        bf16x8 af[4], bfr[4];
#pragma unroll
        for (int i = 0; i < 4; ++i)
            af[i] = *(const bf16x8*)&As[(wm + i * 16 + l16) * 32 + quad * 8];
#pragma unroll
        for (int j = 0; j < 4; ++j)
            bfr[j] = *(const bf16x8*)&Bs[(wn + j * 16 + l16) * 32 + quad * 8];
#pragma unroll
        for (int i = 0; i < 4; ++i)
#pragma unroll
            for (int j = 0; j < 4; ++j)
                acc[i][j] = __builtin_amdgcn_mfma_f32_16x16x32_bf16(af[i], bfr[j], acc[i][j], 0, 0, 0);
        __syncthreads();
    }

    // ---- epilogue: C/D layout col=lane&15, row=quad*4+reg ----
#pragma unroll
    for (int i = 0; i < 4; ++i) {
#pragma unroll
        for (int j = 0; j < 4; ++j) {
            const int gn = bn0 + wn + j * 16 + l16;
            const int gm0 = bm0 + wm + i * 16 + quad * 4;
            if constexpr (EPI == EPI_BIAS || EPI == EPI_RELU) {
                const float b = bias[gn];
#pragma unroll
                for (int r = 0; r < 4; ++r) {
                    float v = acc[i][j][r] + b;
                    if constexpr (EPI == EPI_RELU) v = fmaxf(v, 0.f);
                    C[(size_t)(gm0 + r) * ldc + gn] = f2bf(v);
                }
            } else if constexpr (EPI == EPI_BIAS_T) {
                const float b = bias[gn];
                const int bb = gm0 >> 11, n = gm0 & 2047;
                ushort4 o;
                o.x = f2bf(acc[i][j][0] + b);
                o.y = f2bf(acc[i][j][1] + b);
                o.z = f2bf(acc[i][j][2] + b);
                o.w = f2bf(acc[i][j][3] + b);
                *(ushort4*)&C[((size_t)bb * 512 + gn) * 2048 + n] = o;
            } else if constexpr (EPI == EPI_QKV) {
                const int sel = gn >> 9;     // block-uniform (bn0 128-aligned)
                const int n = gn & 511;
                if (sel == 0) {
                    const float b = bq_[n];
#pragma unroll
                    for (int r = 0; r < 4; ++r)
                        Qo[(size_t)(gm0 + r) * DHID + n] = f2bf(acc[i][j][r] + b);
                } else if (sel == 1) {
                    const float b = bk_[n];
#pragma unroll
                    for (int r = 0; r < 4; ++r)
                        Ko[(size_t)(gm0 + r) * DHID + n] = f2bf(acc[i][j][r] + b);
                } else {
                    const float b = bv_[n];
                    const int bb = gm0 >> 11, nn2 = gm0 & 2047;
                    ushort4 o;
                    o.x = f2bf(acc[i][j][0] + b);
                    o.y = f2bf(acc[i][j][1] + b);
                    o.z = f2bf(acc[i][j][2] + b);
                    o.w = f2bf(acc[i][j][3] + b);
                    *(ushort4*)&Vto[((size_t)bb * 512 + n) * 2048 + nn2] = o;
                }
            } else {
#pragma unroll
                for (int r = 0; r < 4; ++r)
                    C[(size_t)(gm0 + r) * ldc + gn] = f2bf(acc[i][j][r]);
            }
        }
    }
}

// ---------------------------------------------------------------------------
// Fused attention v6b: block = (batch bx, 32 Q-rows by). 4 waves:
// wave w -> rows 16*(w>>1), d-half (w&1)*256.
// v5 raced: Vs staged cross-wave but post-QK^T barrier was lgkm-only -> a
// wave could read Vs rows whose gld_lds (issued by ANOTHER wave) hadn't
// landed. v6b invariant: every wave drains its OWN vmcnt before the
// post-QK^T barrier (__syncthreads does exactly this) -> after it, all
// waves' Vs/kreg loads have landed.
//   * B1 (top): raw lgkm-only barrier (prev PV reads + K ds_writes). The
//     top-of-loop barrier NEVER drains vmcnt (v3's big stall).
//   * K[kt+1] -> registers at top of iter (full-iteration latency window),
//     ds_written into Ks after PV. Ks single-buffered.
//   * Vs via gld_lds at top of iter; drained at B2 (__syncthreads), ~one
//     QK^T phase (~500cy) after issue.
//   * P stripe at head of the wave's OWN Ks chunk (same-wave program order:
//     P write -> pf read -> K ds_write overwrite).
//   * adj/hm register-prefetched one kt ahead.
// ---------------------------------------------------------------------------
__global__ __launch_bounds__(256, 2) void attn_kernel(
    const u16* __restrict__ Q, const u16* __restrict__ K, const u16* __restrict__ Vt,
    const float* __restrict__ adj, const float* __restrict__ hm,
    u16* __restrict__ AO)
{
    extern __shared__ u16 lds[];                 // 65536 B: Ks 32KB | Vs 32KB
    u16* Ks = lds;                               // [ds16][c2][16 rows x 32 u16]
    u16* Vs = lds + 16384;                       // [d512][kv32]

    const int tid = threadIdx.x, wid = tid >> 6, lane = tid & 63;
    const int quad = lane >> 4, l16 = lane & 15;
    const int b = blockIdx.x;                    // batch -> XCD affinity
    const int q0 = blockIdx.y * 32 + (wid >> 1) * 16;  // wave's 16 Q-rows
    const int D0 = (wid & 1) * 256;              // wave's d-half for PV
    const int srow = lane >> 2, sko = (lane & 3) * 8;

    const u16* Qg = Q + (size_t)b * SEQN * DHID;
    const u16* Kg = K + (size_t)b * SEQN * DHID;
    const u16* Vg = Vt + (size_t)b * DHID * SEQN;
    const float* adjg = adj + (size_t)b * SEQN * SEQN;
    u16* AOg = AO + (size_t)b * SEQN * DHID;
    const float* arow = adjg + (size_t)(q0 + quad * 4) * SEQN;
    u16* Plds = Ks + wid * 4096;                 // head of this wave's K chunk

    const float scale = 0.044194173824159216f;   // 1/sqrt(512)

    // Q fragments (A-layout): lane holds Q[q0+l16][ds*32+quad*8+j]
    bf16x8 qf[16];
#pragma unroll
    for (int ds = 0; ds < 16; ++ds)
        qf[ds] = *(const bf16x8*)(Qg + (size_t)(q0 + l16) * DHID + ds * 32 + quad * 8);

    f32x4 oacc[16];
#pragma unroll
    for (int dt = 0; dt < 16; ++dt) oacc[dt] = (f32x4){0.f, 0.f, 0.f, 0.f};
    float lsum[4] = {0.f, 0.f, 0.f, 0.f};

    // ---- prologue: stage Ks = K[0]; adj/hm for kt=0 ----
#pragma unroll
    for (int i = 0; i < 8; ++i) {
        int id = wid * 8 + i, ds = id >> 1, c = id & 1;
        gld_lds16(Kg + (size_t)(c * 16 + srow) * DHID + ds * 32 + sko,
                  &Ks[ds * 1024 + c * 512]);
    }
    float av[8];
#pragma unroll
    for (int r = 0; r < 4; ++r) {
        av[r]     = arow[(size_t)r * SEQN + l16];
        av[4 + r] = arow[(size_t)r * SEQN + 16 + l16];
    }
    float hv0 = hm[l16] * scale;
    float hv1 = hm[16 + l16] * scale;
    asm volatile("s_waitcnt vmcnt(0)" ::: "memory");  // own Ks[0] chunk landed

    for (int kt = 0; kt < 64; ++kt) {
        const int kv0 = kt * 32;

        // [B1] raw barrier (lgkm-only): all waves' K ds_writes + prev PV/pf
        // reads done. Every wave drained its own vmcnt before the PREVIOUS
        // barrier (prologue drain or B2), so all staged data has landed.
        asm volatile("s_waitcnt lgkmcnt(0)" ::: "memory");
        __builtin_amdgcn_s_barrier();
        asm volatile("" ::: "memory");
        __builtin_amdgcn_sched_barrier(0);

        // ---- stage Vs async (drained at B2) ----
#pragma unroll
        for (int i = 0; i < 8; ++i) {
            int id = wid * 8 + i;                // d-rows id*16..id*16+16
            gld_lds16(Vg + (size_t)(id * 16 + srow) * SEQN + kv0 + sko,
                      &Vs[id * 512]);
        }

        // ---- prefetch K[kt+1] into registers (ds_written after PV) ----
        uint4 kreg[8];
        float avn[8] = {0.f, 0.f, 0.f, 0.f, 0.f, 0.f, 0.f, 0.f};
        float hv0n = 0.f, hv1n = 0.f;
        if (kt < 63) {
#pragma unroll
            for (int i = 0; i < 8; ++i) {
                int id = wid * 8 + i, ds = id >> 1, c = id & 1;
                kreg[i] = *(const uint4*)(Kg + (size_t)(kv0 + 32 + c * 16 + srow) * DHID
                                          + ds * 32 + sko);
            }
#pragma unroll
            for (int r = 0; r < 4; ++r) {
                avn[r]     = arow[(size_t)r * SEQN + kv0 + 32 + l16];
                avn[4 + r] = arow[(size_t)r * SEQN + kv0 + 48 + l16];
            }
            hv0n = hm[kv0 + 32 + l16] * scale;
            hv1n = hm[kv0 + 48 + l16] * scale;
        }
        __builtin_amdgcn_sched_barrier(0);       // pin staging issue before QK^T

        // ---- QK^T: S 16x32, 4 independent chains, reads Ks ----
        f32x4 s0a = {0.f,0.f,0.f,0.f}, s0b = {0.f,0.f,0.f,0.f};
        f32x4 s1a = {0.f,0.f,0.f,0.f}, s1b = {0.f,0.f,0.f,0.f};
#pragma unroll
        for (int ds = 0; ds < 16; ds += 2) {
            bf16x8 k00 = *(const bf16x8*)&Ks[ds * 1024 + l16 * 32 + quad * 8];
            bf16x8 k01 = *(const bf16x8*)&Ks[ds * 1024 + 512 + l16 * 32 + quad * 8];
            s0a = __builtin_amdgcn_mfma_f32_16x16x32_bf16(qf[ds], k00, s0a, 0, 0, 0);
            s1a = __builtin_amdgcn_mfma_f32_16x16x32_bf16(qf[ds], k01, s1a, 0, 0, 0);
            bf16x8 k10 = *(const bf16x8*)&Ks[(ds + 1) * 1024 + l16 * 32 + quad * 8];
            bf16x8 k11 = *(const bf16x8*)&Ks[(ds + 1) * 1024 + 512 + l16 * 32 + quad * 8];
            s0b = __builtin_amdgcn_mfma_f32_16x16x32_bf16(qf[ds + 1], k10, s0b, 0, 0, 0);
            s1b = __builtin_amdgcn_mfma_f32_16x16x32_bf16(qf[ds + 1], k11, s1b, 0, 0, 0);
        }
        f32x4 s0 = s0a + s0b, s1 = s1a + s1b;

        // [B2] __syncthreads: drains own vmcnt (Vs + kreg, issued ~1 QK^T
        // phase ago) + lgkm, then barrier. After it: all waves' Vs landed,
        // all Ks reads done -> P may overwrite Ks, PV may read Vs.
        __syncthreads();

        // ---- P = exp(s'), row-sum accumulate, LDS transpose (wave-private) ----
#pragma unroll
        for (int r = 0; r < 4; ++r) {
            float p0 = __expf(s0[r] * av[r] * hv0);
            float p1 = __expf(s1[r] * av[4 + r] * hv1);
            lsum[r] += p0 + p1;
            Plds[(quad * 4 + r) * 40 + l16] = f2bf(p0);
            Plds[(quad * 4 + r) * 40 + 16 + l16] = f2bf(p1);
        }
        asm volatile("s_waitcnt lgkmcnt(0)" ::: "memory");
        __builtin_amdgcn_sched_barrier(0);
        bf16x8 pf = *(const bf16x8*)&Plds[l16 * 40 + quad * 8];

        // ---- PV: O[16 x 256] += P[16x32] @ V[32 x d-half] ----
#pragma unroll
        for (int dt = 0; dt < 16; ++dt) {
            bf16x8 vf = *(const bf16x8*)&Vs[(D0 + dt * 16 + l16) * 32 + quad * 8];
            oacc[dt] = __builtin_amdgcn_mfma_f32_16x16x32_bf16(pf, vf, oacc[dt], 0, 0, 0);
        }

        // ---- ds_write K[kt+1] into this wave's own chunk; rotate scalars ----
        if (kt < 63) {
#pragma unroll
            for (int i = 0; i < 8; ++i) {
                int id = wid * 8 + i, ds = id >> 1, c = id & 1;
                *(uint4*)&Ks[ds * 1024 + c * 512 + lane * 8] = kreg[i];
            }
#pragma unroll
            for (int r = 0; r < 8; ++r) av[r] = avn[r];
            hv0 = hv0n; hv1 = hv1n;
        }
    }

    // ---- finalize: reduce row sums over l16 group, normalize, store ----
#pragma unroll
    for (int r = 0; r < 4; ++r) {
#pragma unroll
        for (int m = 1; m < 16; m <<= 1) lsum[r] += __shfl_xor(lsum[r], m);
        lsum[r] = 1.f / lsum[r];
    }
#pragma unroll
    for (int dt = 0; dt < 16; ++dt) {
#pragma unroll
        for (int r = 0; r < 4; ++r) {
            AOg[(size_t)(q0 + quad * 4 + r) * DHID + D0 + dt * 16 + l16] =
                f2bf(oacc[dt][r] * lsum[r]);
        }
    }
}

// ---------------------------------------------------------------------------
// LN1: x = LN(a + Hf) * g + be   (a bf16, Hf fp32, out bf16)
// ---------------------------------------------------------------------------
__global__ __launch_bounds__(256) void ln_hf32_kernel(
    const u16* __restrict__ a, const float* __restrict__ Hf,
    const float* __restrict__ g, const float* __restrict__ be,
    u16* __restrict__ out)
{
    size_t row = blockIdx.x;
    int t = threadIdx.x, wid = t >> 6, lane = t & 63;
    unsigned int va = *(const unsigned int*)(a + row * (size_t)DHID + t * 2);
    float2 h = *(const float2*)(Hf + row * (size_t)DHID + t * 2);
    float x0 = bf2f((u16)(va & 0xffff)) + h.x;
    float x1 = bf2f((u16)(va >> 16)) + h.y;
    float s = x0 + x1, sq = x0 * x0 + x1 * x1;
#pragma unroll
    for (int m = 1; m < 64; m <<= 1) { s += __shfl_xor(s, m); sq += __shfl_xor(sq, m); }
    __shared__ float rs[4], rq[4];
    if (lane == 0) { rs[wid] = s; rq[wid] = sq; }
    __syncthreads();
    s = rs[0] + rs[1] + rs[2] + rs[3];
    sq = rq[0] + rq[1] + rq[2] + rq[3];
    float mean = s * (1.f / (float)DHID);
    float var = sq * (1.f / (float)DHID) - mean * mean;
    float rstd = rsqrtf(var + 1e-5f);
    float2 vg = *(const float2*)(g + t * 2);
    float2 vbe = *(const float2*)(be + t * 2);
    float y0 = (x0 - mean) * rstd * vg.x + vbe.x;
    float y1 = (x1 - mean) * rstd * vg.y + vbe.y;
    unsigned int o = (unsigned int)f2bf(y0) | ((unsigned int)f2bf(y1) << 16);
    *(unsigned int*)(out + row * (size_t)DHID + t * 2) = o;
}

// ---------------------------------------------------------------------------
// LN2: out = LN(a + b) * g + be   (a,b bf16, out fp32)
// ---------------------------------------------------------------------------
__global__ __launch_bounds__(256) void ln_kernel_f32out(
    const u16* __restrict__ a, const u16* __restrict__ bp,
    const float* __restrict__ g, const float* __restrict__ be,
    float* __restrict__ out)
{
    size_t row = blockIdx.x;
    int t = threadIdx.x, wid = t >> 6, lane = t & 63;
    unsigned int va = *(const unsigned int*)(a + row * (size_t)DHID + t * 2);
    unsigned int vb = *(const unsigned int*)(bp + row * (size_t)DHID + t * 2);
    float x0 = bf2f((u16)(va & 0xffff)) + bf2f((u16)(vb & 0xffff));
    float x1 = bf2f((u16)(va >> 16)) + bf2f((u16)(vb >> 16));
    float s = x0 + x1, sq = x0 * x0 + x1 * x1;
#pragma unroll
    for (int m = 1; m < 64; m <<= 1) { s += __shfl_xor(s, m); sq += __shfl_xor(sq, m); }
    __shared__ float rs[4], rq[4];
    if (lane == 0) { rs[wid] = s; rq[wid] = sq; }
    __syncthreads();
    s = rs[0] + rs[1] + rs[2] + rs[3];
    sq = rq[0] + rq[1] + rq[2] + rq[3];
    float mean = s * (1.f / (float)DHID);
    float var = sq * (1.f / (float)DHID) - mean * mean;
    float rstd = rsqrtf(var + 1e-5f);
    float2 vg = *(const float2*)(g + t * 2);
    float2 vbe = *(const float2*)(be + t * 2);
    float y0 = (x0 - mean) * rstd * vg.x + vbe.x;
    float y1 = (x1 - mean) * rstd * vg.y + vbe.y;
    *(float2*)(out + row * (size_t)DHID + t * 2) = make_float2(y0, y1);
}

// ---------------------------------------------------------------------------
extern "C" void kernel_launch(void* const* d_in, const int* in_sizes, int n_in,
                              void* d_out, int out_size, void* d_ws, size_t ws_size,
                              hipStream_t stream) {
    const float* H   = (const float*)d_in[0];
    const float* adj = (const float*)d_in[1];
    const float* hop = (const float*)d_in[2];
    const float* Wq  = (const float*)d_in[3];
    const float* bq  = (const float*)d_in[4];
    const float* Wk  = (const float*)d_in[5];
    const float* bk  = (const float*)d_in[6];
    const float* Wv  = (const float*)d_in[7];
    const float* bv  = (const float*)d_in[8];
    const float* W1  = (const float*)d_in[9];
    const float* b1  = (const float*)d_in[10];
    const float* W2  = (const float*)d_in[11];
    const float* b2  = (const float*)d_in[12];
    const float* g1  = (const float*)d_in[13];
    const float* be1 = (const float*)d_in[14];
    const float* g2  = (const float*)d_in[15];
    const float* be2 = (const float*)d_in[16];

    const size_t MiB = 1ull << 20;
    char* w = (char*)d_ws;
    float* hm   = (float*)w;                      // 8 KB
    u16* Hb    = (u16*)(w + 1 * MiB);             // 16 MiB
    u16* Wqkvt = (u16*)(w + 17 * MiB);            // 1.5 MiB [Wq^T|Wk^T|Wv^T]
    u16* W1t   = (u16*)(w + 18 * MiB + 512 * 1024); // 1 MiB
    u16* W2t   = (u16*)(w + 19 * MiB + 512 * 1024); // 1 MiB
    u16* Q     = (u16*)(w + 21 * MiB);            // 16 MiB
    u16* Kb    = (u16*)(w + 37 * MiB);            // 16 MiB
    u16* Vt    = (u16*)(w + 53 * MiB);            // 16 MiB  [b][512][2048]
    u16* AO    = (u16*)(w + 69 * MiB);            // 16 MiB
    u16* HID   = (u16*)(w + 85 * MiB);            // 32 MiB -> total 117 MiB
    // aliases (lifetimes disjoint):
    u16* X   = Kb;   // LN1 output (K dead after attention)
    u16* F2  = Vt;   // ffn2 output (V dead after attention)

    const int BN = 8, N = SEQN, D = DHID;

    // fp32 -> bf16 conversions (weights transposed, QKV concatenated)
    cvt_kernel<<<(BN * N * D) / (8 * 256), 256, 0, stream>>>(H, Hb, BN * N * D);
    cvt_t_kernel<<<(D * D + 255) / 256, 256, 0, stream>>>(Wq, Wqkvt, D, D);
    cvt_t_kernel<<<(D * D + 255) / 256, 256, 0, stream>>>(Wk, Wqkvt + D * D, D, D);
    cvt_t_kernel<<<(D * D + 255) / 256, 256, 0, stream>>>(Wv, Wqkvt + 2 * D * D, D, D);
    cvt_t_kernel<<<(D * 2 * D + 255) / 256, 256, 0, stream>>>(W1, W1t, D, 2 * D);
    cvt_t_kernel<<<(2 * D * D + 255) / 256, 256, 0, stream>>>(W2, W2t, 2 * D, D);

    hmean_kernel<<<N, 64, 0, stream>>>(hop, hm);

    // fused QKV: C[16384,1536] over [Q|K|Vt] outputs
    gemm_bt<EPI_QKV><<<dim3(12, 128, 1), 256, 0, stream>>>(
        Hb, Wqkvt, nullptr, nullptr, D, D, D, 0, Q, Kb, Vt, bq, bk, bv);

    // fused attention: 512 blocks (8 batches x 64 stripes of 32 rows), 2/CU
    attn_kernel<<<dim3(8, 64), 256, 65536, stream>>>(Q, Kb, Vt, adj, hm, AO);

    // x = LN(attn_out + H)
    ln_hf32_kernel<<<BN * N, 256, 0, stream>>>(AO, H, g1, be1, X);

    // hid = relu(x @ W1 + b1)
    gemm_bt<EPI_RELU><<<dim3(8, 128, 1), 256, 0, stream>>>(
        X, W1t, HID, b1, D, D, D, 2 * D, nullptr, nullptr, nullptr, nullptr, nullptr, nullptr);

    // f2 = hid @ W2 + b2
    gemm_bt<EPI_BIAS><<<dim3(4, 128, 1), 256, 0, stream>>>(
        HID, W2t, F2, b2, 2 * D, 2 * D, 2 * D, D, nullptr, nullptr, nullptr, nullptr, nullptr, nullptr);

    // out = LN(f2 + x)  -> fp32 d_out
    ln_kernel_f32out<<<BN * N, 256, 0, stream>>>(F2, X, g2, be2, (float*)d_out);
}

// Round 5
// 565.843 us; speedup vs baseline: 1.4796x; 1.4796x over previous
//
#include <hip/hip_runtime.h>

typedef unsigned short u16;
typedef __bf16 bf16x8 __attribute__((ext_vector_type(8)));
typedef float f32x4 __attribute__((ext_vector_type(4)));

// Problem constants: B=8, N=2048, DH=512
#define SEQN 2048
#define DHID 512

static __device__ __forceinline__ float bf2f(u16 u) {
    union { unsigned int i; float f; } c; c.i = ((unsigned int)u) << 16; return c.f;
}
static __device__ __forceinline__ u16 f2bf(float f) {
    union { float f; unsigned int i; } c; c.f = f;
    unsigned int x = c.i;
    return (u16)((x + 0x7fffu + ((x >> 16) & 1u)) >> 16);
}

// async global->LDS, 16B per lane, LDS dest = wave-uniform base + lane*16
static __device__ __forceinline__ void gld_lds16(const u16* g, u16* l) {
    __builtin_amdgcn_global_load_lds(
        (__attribute__((address_space(1))) void*)(g),
        (__attribute__((address_space(3))) void*)(l), 16, 0, 0);
}

// ---------------------------------------------------------------------------
// fp32 -> bf16 conversion (n multiple of 8)
// ---------------------------------------------------------------------------
__global__ __launch_bounds__(256) void cvt_kernel(const float* __restrict__ src,
                                                  u16* __restrict__ dst, int n) {
    int i = (blockIdx.x * 256 + threadIdx.x) * 8;
    if (i >= n) return;
    float4 a = *(const float4*)(src + i);
    float4 b = *(const float4*)(src + i + 4);
    union { uint4 u; u16 s[8]; } o;
    o.s[0] = f2bf(a.x); o.s[1] = f2bf(a.y); o.s[2] = f2bf(a.z); o.s[3] = f2bf(a.w);
    o.s[4] = f2bf(b.x); o.s[5] = f2bf(b.y); o.s[6] = f2bf(b.z); o.s[7] = f2bf(b.w);
    *(uint4*)(dst + i) = o.u;
}

// fp32 [K][N] -> bf16 transposed [N][K]
__global__ __launch_bounds__(256) void cvt_t_kernel(const float* __restrict__ src,
                                                    u16* __restrict__ dst, int K, int N) {
    int idx = blockIdx.x * 256 + threadIdx.x;
    if (idx >= K * N) return;
    int n = idx / K, k = idx - n * K;
    dst[idx] = f2bf(src[(size_t)k * N + n]);
}

// ---------------------------------------------------------------------------
// hop_emb row means (fp32 in): hm[j] = mean_d hop_emb[j][d]
// ---------------------------------------------------------------------------
__global__ void hmean_kernel(const float* __restrict__ hop, float* __restrict__ hm) {
    int j = blockIdx.x, t = threadIdx.x;           // 64 threads
    const float* p = hop + (size_t)j * DHID + t * 8;
    float4 a = *(const float4*)p;
    float4 b = *(const float4*)(p + 4);
    float s = a.x + a.y + a.z + a.w + b.x + b.y + b.z + b.w;
#pragma unroll
    for (int m = 1; m < 64; m <<= 1) s += __shfl_xor(s, m);
    if (t == 0) hm[j] = s * (1.0f / (float)DHID);
}

// ---------------------------------------------------------------------------
// BT MFMA GEMM: C[M,N] = A[M,K] * Bt[N,K]^T + epilogue  (A,Bt,C bf16)
// Tile 128x128x32, 256 threads (4 waves as 2x2 of 64x64), 16x16x32 MFMA.
// EPI_QKV: N=1536 concat [Q|K|Vt]; sel = gn>>9 is block-uniform.
// ---------------------------------------------------------------------------
enum { EPI_BIAS = 0, EPI_RELU = 1, EPI_PLAIN = 3, EPI_BIAS_T = 4, EPI_QKV = 5 };

template <int EPI>
__global__ __launch_bounds__(256) void gemm_bt(
    const u16* __restrict__ A, const u16* __restrict__ Bt, u16* __restrict__ C,
    const float* __restrict__ bias,
    int K, int lda, int ldb, int ldc,
    u16* __restrict__ Qo, u16* __restrict__ Ko, u16* __restrict__ Vto,
    const float* __restrict__ bq_, const float* __restrict__ bk_,
    const float* __restrict__ bv_)
{
    __shared__ u16 As[128 * 32];   // 8 KB, [row][k], row stride 64 B
    __shared__ u16 Bs[128 * 32];   // 8 KB, [n][k]

    const int tid = threadIdx.x;
    const u16* Ab = A;
    const u16* Bb = Bt;

    const int bm0 = blockIdx.y * 128, bn0 = blockIdx.x * 128;
    const int wid = tid >> 6, lane = tid & 63, quad = lane >> 4, l16 = lane & 15;
    const int wm = (wid >> 1) * 64, wn = (wid & 1) * 64;
    const int srow = lane >> 2;            // 0..15: row within 16-row chunk
    const int skof = (lane & 3) * 8;       // k element offset (8 bf16 = 16 B)

    f32x4 acc[4][4];
#pragma unroll
    for (int i = 0; i < 4; ++i)
#pragma unroll
        for (int j = 0; j < 4; ++j) acc[i][j] = (f32x4){0.f, 0.f, 0.f, 0.f};

    for (int k0 = 0; k0 < K; k0 += 32) {
#pragma unroll
        for (int it = 0; it < 2; ++it) {
            int c = wid * 2 + it;          // wave-uniform
            gld_lds16(Ab + (size_t)(bm0 + c * 16 + srow) * lda + k0 + skof,
                      &As[c * 512]);
        }
#pragma unroll
        for (int it = 0; it < 2; ++it) {
            int c = wid * 2 + it;
            gld_lds16(Bb + (size_t)(bn0 + c * 16 + srow) * ldb + k0 + skof,
                      &Bs[c * 512]);
        }
        __syncthreads();

        bf16x8 af[4], bfr[4];
#pragma unroll
        for (int i = 0; i < 4; ++i)
            af[i] = *(const bf16x8*)&As[(wm + i * 16 + l16) * 32 + quad * 8];
#pragma unroll
        for (int j = 0; j < 4; ++j)
            bfr[j] = *(const bf16x8*)&Bs[(wn + j * 16 + l16) * 32 + quad * 8];
#pragma unroll
        for (int i = 0; i < 4; ++i)
#pragma unroll
            for (int j = 0; j < 4; ++j)
                acc[i][j] = __builtin_amdgcn_mfma_f32_16x16x32_bf16(af[i], bfr[j], acc[i][j], 0, 0, 0);
        __syncthreads();
    }

    // ---- epilogue: C/D layout col=lane&15, row=quad*4+reg ----
#pragma unroll
    for (int i = 0; i < 4; ++i) {
#pragma unroll
        for (int j = 0; j < 4; ++j) {
            const int gn = bn0 + wn + j * 16 + l16;
            const int gm0 = bm0 + wm + i * 16 + quad * 4;
            if constexpr (EPI == EPI_BIAS || EPI == EPI_RELU) {
                const float b = bias[gn];
#pragma unroll
                for (int r = 0; r < 4; ++r) {
                    float v = acc[i][j][r] + b;
                    if constexpr (EPI == EPI_RELU) v = fmaxf(v, 0.f);
                    C[(size_t)(gm0 + r) * ldc + gn] = f2bf(v);
                }
            } else if constexpr (EPI == EPI_BIAS_T) {
                const float b = bias[gn];
                const int bb = gm0 >> 11, n = gm0 & 2047;
                ushort4 o;
                o.x = f2bf(acc[i][j][0] + b);
                o.y = f2bf(acc[i][j][1] + b);
                o.z = f2bf(acc[i][j][2] + b);
                o.w = f2bf(acc[i][j][3] + b);
                *(ushort4*)&C[((size_t)bb * 512 + gn) * 2048 + n] = o;
            } else if constexpr (EPI == EPI_QKV) {
                const int sel = gn >> 9;     // block-uniform (bn0 128-aligned)
                const int n = gn & 511;
                if (sel == 0) {
                    const float b = bq_[n];
#pragma unroll
                    for (int r = 0; r < 4; ++r)
                        Qo[(size_t)(gm0 + r) * DHID + n] = f2bf(acc[i][j][r] + b);
                } else if (sel == 1) {
                    const float b = bk_[n];
#pragma unroll
                    for (int r = 0; r < 4; ++r)
                        Ko[(size_t)(gm0 + r) * DHID + n] = f2bf(acc[i][j][r] + b);
                } else {
                    const float b = bv_[n];
                    const int bb = gm0 >> 11, nn2 = gm0 & 2047;
                    ushort4 o;
                    o.x = f2bf(acc[i][j][0] + b);
                    o.y = f2bf(acc[i][j][1] + b);
                    o.z = f2bf(acc[i][j][2] + b);
                    o.w = f2bf(acc[i][j][3] + b);
                    *(ushort4*)&Vto[((size_t)bb * 512 + n) * 2048 + nn2] = o;
                }
            } else {
#pragma unroll
                for (int r = 0; r < 4; ++r)
                    C[(size_t)(gm0 + r) * ldc + gn] = f2bf(acc[i][j][r]);
            }
        }
    }
}

// ---------------------------------------------------------------------------
// Fused attention v7: block = (batch bx, 32 Q-rows by). 4 waves:
// wave w -> rows 16*(w>>1), d-half (w&1)*256.
// v3 stalled on the exposed K-stage drain (staged then immediately drained at
// a __syncthreads). v6b fixed that with register prefetch but spilled (~750MB
// scratch writes/dispatch). v7 gets the same pipelining with ZERO extra
// registers: K stays gld_lds-staged, but its issue point moves to right
// after B2 (post-QK^T barrier), so softmax+PV (~400cy) cover its latency.
// P gets a dedicated LDS stripe (no longer aliases Ks), which is what makes
// the early K restage legal. 2 barriers/iter (both plain __syncthreads, so
// every wave drains its own vmcnt before each barrier -> after a barrier all
// waves' staged LDS data has landed; this is the invariant v5 broke).
//   B1 (top): drains K[kt] stage (issued last iter, covered by softmax+PV);
//             orders prev PV Vs-reads before Vs restage.
//   B2: drains Vs[kt] (issued at top, covered by QK^T); orders Ks reads
//       before K[kt+1] restage.
// LDS 69KB: Ks 32KB | Vs 32KB | P 5KB -> still 2 blocks/CU.
// ---------------------------------------------------------------------------
__global__ __launch_bounds__(256, 2) void attn_kernel(
    const u16* __restrict__ Q, const u16* __restrict__ K, const u16* __restrict__ Vt,
    const float* __restrict__ adj, const float* __restrict__ hm,
    u16* __restrict__ AO)
{
    extern __shared__ u16 lds[];                 // 70656 B
    u16* Ks = lds;                               // [ds16][c2][16 rows x 32 u16]
    u16* Vs = lds + 16384;                       // [d512][kv32]
    u16* Pb = lds + 32768;                       // 4 waves x 640 u16

    const int tid = threadIdx.x, wid = tid >> 6, lane = tid & 63;
    const int quad = lane >> 4, l16 = lane & 15;
    const int b = blockIdx.x;                    // batch -> XCD affinity
    const int q0 = blockIdx.y * 32 + (wid >> 1) * 16;  // wave's 16 Q-rows
    const int D0 = (wid & 1) * 256;              // wave's d-half for PV
    const int srow = lane >> 2, sko = (lane & 3) * 8;

    const u16* Qg = Q + (size_t)b * SEQN * DHID;
    const u16* Kg = K + (size_t)b * SEQN * DHID;
    const u16* Vg = Vt + (size_t)b * DHID * SEQN;
    const float* adjg = adj + (size_t)b * SEQN * SEQN;
    u16* AOg = AO + (size_t)b * SEQN * DHID;
    const float* arow = adjg + (size_t)(q0 + quad * 4) * SEQN;
    u16* Plds = Pb + wid * 640;                  // wave-private 16 x 40 u16

    const float scale = 0.044194173824159216f;   // 1/sqrt(512)

    // Q fragments (A-layout): lane holds Q[q0+l16][ds*32+quad*8+j]
    bf16x8 qf[16];
#pragma unroll
    for (int ds = 0; ds < 16; ++ds)
        qf[ds] = *(const bf16x8*)(Qg + (size_t)(q0 + l16) * DHID + ds * 32 + quad * 8);

    f32x4 oacc[16];
#pragma unroll
    for (int dt = 0; dt < 16; ++dt) oacc[dt] = (f32x4){0.f, 0.f, 0.f, 0.f};
    float lsum[4] = {0.f, 0.f, 0.f, 0.f};

    // ---- prologue: issue Ks = K[0] staging; drained by first B1 ----
#pragma unroll
    for (int i = 0; i < 8; ++i) {
        int id = wid * 8 + i, ds = id >> 1, c = id & 1;
        gld_lds16(Kg + (size_t)(c * 16 + srow) * DHID + ds * 32 + sko,
                  &Ks[ds * 1024 + c * 512]);
    }

    for (int kt = 0; kt < 64; ++kt) {
        const int kv0 = kt * 32;

        // [B1] drains own vmcnt (K[kt] stage) + lgkm (prev PV reads), barrier.
        __syncthreads();

        // ---- stage Vs[kt] async (drained at B2, covered by QK^T) ----
#pragma unroll
        for (int i = 0; i < 8; ++i) {
            int id = wid * 8 + i;                // d-rows id*16..id*16+16
            gld_lds16(Vg + (size_t)(id * 16 + srow) * SEQN + kv0 + sko,
                      &Vs[id * 512]);
        }

        // ---- early scalar loads (used in softmax, covered by QK^T) ----
        float hv0 = hm[kv0 + l16] * scale;
        float hv1 = hm[kv0 + 16 + l16] * scale;
        float av[8];
#pragma unroll
        for (int r = 0; r < 4; ++r) {
            av[r]     = arow[(size_t)r * SEQN + kv0 + l16];
            av[4 + r] = arow[(size_t)r * SEQN + kv0 + 16 + l16];
        }

        // ---- QK^T: S 16x32, 4 independent chains, reads Ks ----
        f32x4 s0a = {0.f,0.f,0.f,0.f}, s0b = {0.f,0.f,0.f,0.f};
        f32x4 s1a = {0.f,0.f,0.f,0.f}, s1b = {0.f,0.f,0.f,0.f};
#pragma unroll
        for (int ds = 0; ds < 16; ds += 2) {
            bf16x8 k00 = *(const bf16x8*)&Ks[ds * 1024 + l16 * 32 + quad * 8];
            bf16x8 k01 = *(const bf16x8*)&Ks[ds * 1024 + 512 + l16 * 32 + quad * 8];
            s0a = __builtin_amdgcn_mfma_f32_16x16x32_bf16(qf[ds], k00, s0a, 0, 0, 0);
            s1a = __builtin_amdgcn_mfma_f32_16x16x32_bf16(qf[ds], k01, s1a, 0, 0, 0);
            bf16x8 k10 = *(const bf16x8*)&Ks[(ds + 1) * 1024 + l16 * 32 + quad * 8];
            bf16x8 k11 = *(const bf16x8*)&Ks[(ds + 1) * 1024 + 512 + l16 * 32 + quad * 8];
            s0b = __builtin_amdgcn_mfma_f32_16x16x32_bf16(qf[ds + 1], k10, s0b, 0, 0, 0);
            s1b = __builtin_amdgcn_mfma_f32_16x16x32_bf16(qf[ds + 1], k11, s1b, 0, 0, 0);
        }
        f32x4 s0 = s0a + s0b, s1 = s1a + s1b;

        // [B2] drains own vmcnt (Vs + scalars) + lgkm (Ks reads), barrier.
        // After: all waves' Vs landed; no wave reads Ks[kt] again.
        __syncthreads();

        // ---- stage Ks[kt+1] NOW (issue early; softmax+PV cover latency;
        //      drained at next B1) ----
        if (kt < 63) {
#pragma unroll
            for (int i = 0; i < 8; ++i) {
                int id = wid * 8 + i, ds = id >> 1, c = id & 1;
                gld_lds16(Kg + (size_t)(kv0 + 32 + c * 16 + srow) * DHID + ds * 32 + sko,
                          &Ks[ds * 1024 + c * 512]);
            }
        }
        __builtin_amdgcn_sched_barrier(0);       // keep K issue above softmax/PV

        // ---- P = exp(s'), row-sum accumulate, LDS transpose (wave-private) ----
#pragma unroll
        for (int r = 0; r < 4; ++r) {
            float p0 = __expf(s0[r] * av[r] * hv0);
            float p1 = __expf(s1[r] * av[4 + r] * hv1);
            lsum[r] += p0 + p1;
            Plds[(quad * 4 + r) * 40 + l16] = f2bf(p0);
            Plds[(quad * 4 + r) * 40 + 16 + l16] = f2bf(p1);
        }
        asm volatile("s_waitcnt lgkmcnt(0)" ::: "memory");
        __builtin_amdgcn_sched_barrier(0);
        bf16x8 pf = *(const bf16x8*)&Plds[l16 * 40 + quad * 8];

        // ---- PV: O[16 x 256] += P[16x32] @ V[32 x d-half] ----
#pragma unroll
        for (int dt = 0; dt < 16; ++dt) {
            bf16x8 vf = *(const bf16x8*)&Vs[(D0 + dt * 16 + l16) * 32 + quad * 8];
            oacc[dt] = __builtin_amdgcn_mfma_f32_16x16x32_bf16(pf, vf, oacc[dt], 0, 0, 0);
        }
    }

    // ---- finalize: reduce row sums over l16 group, normalize, store ----
#pragma unroll
    for (int r = 0; r < 4; ++r) {
#pragma unroll
        for (int m = 1; m < 16; m <<= 1) lsum[r] += __shfl_xor(lsum[r], m);
        lsum[r] = 1.f / lsum[r];
    }
#pragma unroll
    for (int dt = 0; dt < 16; ++dt) {
#pragma unroll
        for (int r = 0; r < 4; ++r) {
            AOg[(size_t)(q0 + quad * 4 + r) * DHID + D0 + dt * 16 + l16] =
                f2bf(oacc[dt][r] * lsum[r]);
        }
    }
}

// ---------------------------------------------------------------------------
// LN1: x = LN(a + Hf) * g + be   (a bf16, Hf fp32, out bf16)
// ---------------------------------------------------------------------------
__global__ __launch_bounds__(256) void ln_hf32_kernel(
    const u16* __restrict__ a, const float* __restrict__ Hf,
    const float* __restrict__ g, const float* __restrict__ be,
    u16* __restrict__ out)
{
    size_t row = blockIdx.x;
    int t = threadIdx.x, wid = t >> 6, lane = t & 63;
    unsigned int va = *(const unsigned int*)(a + row * (size_t)DHID + t * 2);
    float2 h = *(const float2*)(Hf + row * (size_t)DHID + t * 2);
    float x0 = bf2f((u16)(va & 0xffff)) + h.x;
    float x1 = bf2f((u16)(va >> 16)) + h.y;
    float s = x0 + x1, sq = x0 * x0 + x1 * x1;
#pragma unroll
    for (int m = 1; m < 64; m <<= 1) { s += __shfl_xor(s, m); sq += __shfl_xor(sq, m); }
    __shared__ float rs[4], rq[4];
    if (lane == 0) { rs[wid] = s; rq[wid] = sq; }
    __syncthreads();
    s = rs[0] + rs[1] + rs[2] + rs[3];
    sq = rq[0] + rq[1] + rq[2] + rq[3];
    float mean = s * (1.f / (float)DHID);
    float var = sq * (1.f / (float)DHID) - mean * mean;
    float rstd = rsqrtf(var + 1e-5f);
    float2 vg = *(const float2*)(g + t * 2);
    float2 vbe = *(const float2*)(be + t * 2);
    float y0 = (x0 - mean) * rstd * vg.x + vbe.x;
    float y1 = (x1 - mean) * rstd * vg.y + vbe.y;
    unsigned int o = (unsigned int)f2bf(y0) | ((unsigned int)f2bf(y1) << 16);
    *(unsigned int*)(out + row * (size_t)DHID + t * 2) = o;
}

// ---------------------------------------------------------------------------
// LN2: out = LN(a + b) * g + be   (a,b bf16, out fp32)
// ---------------------------------------------------------------------------
__global__ __launch_bounds__(256) void ln_kernel_f32out(
    const u16* __restrict__ a, const u16* __restrict__ bp,
    const float* __restrict__ g, const float* __restrict__ be,
    float* __restrict__ out)
{
    size_t row = blockIdx.x;
    int t = threadIdx.x, wid = t >> 6, lane = t & 63;
    unsigned int va = *(const unsigned int*)(a + row * (size_t)DHID + t * 2);
    unsigned int vb = *(const unsigned int*)(bp + row * (size_t)DHID + t * 2);
    float x0 = bf2f((u16)(va & 0xffff)) + bf2f((u16)(vb & 0xffff));
    float x1 = bf2f((u16)(va >> 16)) + bf2f((u16)(vb >> 16));
    float s = x0 + x1, sq = x0 * x0 + x1 * x1;
#pragma unroll
    for (int m = 1; m < 64; m <<= 1) { s += __shfl_xor(s, m); sq += __shfl_xor(sq, m); }
    __shared__ float rs[4], rq[4];
    if (lane == 0) { rs[wid] = s; rq[wid] = sq; }
    __syncthreads();
    s = rs[0] + rs[1] + rs[2] + rs[3];
    sq = rq[0] + rq[1] + rq[2] + rq[3];
    float mean = s * (1.f / (float)DHID);
    float var = sq * (1.f / (float)DHID) - mean * mean;
    float rstd = rsqrtf(var + 1e-5f);
    float2 vg = *(const float2*)(g + t * 2);
    float2 vbe = *(const float2*)(be + t * 2);
    float y0 = (x0 - mean) * rstd * vg.x + vbe.x;
    float y1 = (x1 - mean) * rstd * vg.y + vbe.y;
    *(float2*)(out + row * (size_t)DHID + t * 2) = make_float2(y0, y1);
}

// ---------------------------------------------------------------------------
extern "C" void kernel_launch(void* const* d_in, const int* in_sizes, int n_in,
                              void* d_out, int out_size, void* d_ws, size_t ws_size,
                              hipStream_t stream) {
    const float* H   = (const float*)d_in[0];
    const float* adj = (const float*)d_in[1];
    const float* hop = (const float*)d_in[2];
    const float* Wq  = (const float*)d_in[3];
    const float* bq  = (const float*)d_in[4];
    const float* Wk  = (const float*)d_in[5];
    const float* bk  = (const float*)d_in[6];
    const float* Wv  = (const float*)d_in[7];
    const float* bv  = (const float*)d_in[8];
    const float* W1  = (const float*)d_in[9];
    const float* b1  = (const float*)d_in[10];
    const float* W2  = (const float*)d_in[11];
    const float* b2  = (const float*)d_in[12];
    const float* g1  = (const float*)d_in[13];
    const float* be1 = (const float*)d_in[14];
    const float* g2  = (const float*)d_in[15];
    const float* be2 = (const float*)d_in[16];

    const size_t MiB = 1ull << 20;
    char* w = (char*)d_ws;
    float* hm   = (float*)w;                      // 8 KB
    u16* Hb    = (u16*)(w + 1 * MiB);             // 16 MiB
    u16* Wqkvt = (u16*)(w + 17 * MiB);            // 1.5 MiB [Wq^T|Wk^T|Wv^T]
    u16* W1t   = (u16*)(w + 18 * MiB + 512 * 1024); // 1 MiB
    u16* W2t   = (u16*)(w + 19 * MiB + 512 * 1024); // 1 MiB
    u16* Q     = (u16*)(w + 21 * MiB);            // 16 MiB
    u16* Kb    = (u16*)(w + 37 * MiB);            // 16 MiB
    u16* Vt    = (u16*)(w + 53 * MiB);            // 16 MiB  [b][512][2048]
    u16* AO    = (u16*)(w + 69 * MiB);            // 16 MiB
    u16* HID   = (u16*)(w + 85 * MiB);            // 32 MiB -> total 117 MiB
    // aliases (lifetimes disjoint):
    u16* X   = Kb;   // LN1 output (K dead after attention)
    u16* F2  = Vt;   // ffn2 output (V dead after attention)

    const int BN = 8, N = SEQN, D = DHID;

    // fp32 -> bf16 conversions (weights transposed, QKV concatenated)
    cvt_kernel<<<(BN * N * D) / (8 * 256), 256, 0, stream>>>(H, Hb, BN * N * D);
    cvt_t_kernel<<<(D * D + 255) / 256, 256, 0, stream>>>(Wq, Wqkvt, D, D);
    cvt_t_kernel<<<(D * D + 255) / 256, 256, 0, stream>>>(Wk, Wqkvt + D * D, D, D);
    cvt_t_kernel<<<(D * D + 255) / 256, 256, 0, stream>>>(Wv, Wqkvt + 2 * D * D, D, D);
    cvt_t_kernel<<<(D * 2 * D + 255) / 256, 256, 0, stream>>>(W1, W1t, D, 2 * D);
    cvt_t_kernel<<<(2 * D * D + 255) / 256, 256, 0, stream>>>(W2, W2t, 2 * D, D);

    hmean_kernel<<<N, 64, 0, stream>>>(hop, hm);

    // fused QKV: C[16384,1536] over [Q|K|Vt] outputs
    gemm_bt<EPI_QKV><<<dim3(12, 128, 1), 256, 0, stream>>>(
        Hb, Wqkvt, nullptr, nullptr, D, D, D, 0, Q, Kb, Vt, bq, bk, bv);

    // fused attention: 512 blocks (8 batches x 64 stripes of 32 rows), 2/CU
    attn_kernel<<<dim3(8, 64), 256, 70656, stream>>>(Q, Kb, Vt, adj, hm, AO);

    // x = LN(attn_out + H)
    ln_hf32_kernel<<<BN * N, 256, 0, stream>>>(AO, H, g1, be1, X);

    // hid = relu(x @ W1 + b1)
    gemm_bt<EPI_RELU><<<dim3(8, 128, 1), 256, 0, stream>>>(
        X, W1t, HID, b1, D, D, D, 2 * D, nullptr, nullptr, nullptr, nullptr, nullptr, nullptr);

    // f2 = hid @ W2 + b2
    gemm_bt<EPI_BIAS><<<dim3(4, 128, 1), 256, 0, stream>>>(
        HID, W2t, F2, b2, 2 * D, 2 * D, 2 * D, D, nullptr, nullptr, nullptr, nullptr, nullptr, nullptr);

    // out = LN(f2 + x)  -> fp32 d_out
    ln_kernel_f32out<<<BN * N, 256, 0, stream>>>(F2, X, g2, be2, (float*)d_out);
}

// Round 6
// 556.201 us; speedup vs baseline: 1.5052x; 1.0173x over previous
//
#include <hip/hip_runtime.h>

typedef unsigned short u16;
typedef __bf16 bf16x8 __attribute__((ext_vector_type(8)));
typedef float f32x4 __attribute__((ext_vector_type(4)));

// Problem constants: B=8, N=2048, DH=512
#define SEQN 2048
#define DHID 512

static __device__ __forceinline__ float bf2f(u16 u) {
    union { unsigned int i; float f; } c; c.i = ((unsigned int)u) << 16; return c.f;
}
static __device__ __forceinline__ u16 f2bf(float f) {
    union { float f; unsigned int i; } c; c.f = f;
    unsigned int x = c.i;
    return (u16)((x + 0x7fffu + ((x >> 16) & 1u)) >> 16);
}

// async global->LDS, 16B per lane, LDS dest = wave-uniform base + lane*16
static __device__ __forceinline__ void gld_lds16(const u16* g, u16* l) {
    __builtin_amdgcn_global_load_lds(
        (__attribute__((address_space(1))) void*)(g),
        (__attribute__((address_space(3))) void*)(l), 16, 0, 0);
}

// ---------------------------------------------------------------------------
// fp32 -> bf16 conversion (n multiple of 8)
// ---------------------------------------------------------------------------
__global__ __launch_bounds__(256) void cvt_kernel(const float* __restrict__ src,
                                                  u16* __restrict__ dst, int n) {
    int i = (blockIdx.x * 256 + threadIdx.x) * 8;
    if (i >= n) return;
    float4 a = *(const float4*)(src + i);
    float4 b = *(const float4*)(src + i + 4);
    union { uint4 u; u16 s[8]; } o;
    o.s[0] = f2bf(a.x); o.s[1] = f2bf(a.y); o.s[2] = f2bf(a.z); o.s[3] = f2bf(a.w);
    o.s[4] = f2bf(b.x); o.s[5] = f2bf(b.y); o.s[6] = f2bf(b.z); o.s[7] = f2bf(b.w);
    *(uint4*)(dst + i) = o.u;
}

// fp32 [K][N] -> bf16 transposed [N][K]
__global__ __launch_bounds__(256) void cvt_t_kernel(const float* __restrict__ src,
                                                    u16* __restrict__ dst, int K, int N) {
    int idx = blockIdx.x * 256 + threadIdx.x;
    if (idx >= K * N) return;
    int n = idx / K, k = idx - n * K;
    dst[idx] = f2bf(src[(size_t)k * N + n]);
}

// ---------------------------------------------------------------------------
// hop_emb row means (fp32 in): hm[j] = mean_d hop_emb[j][d]
// ---------------------------------------------------------------------------
__global__ void hmean_kernel(const float* __restrict__ hop, float* __restrict__ hm) {
    int j = blockIdx.x, t = threadIdx.x;           // 64 threads
    const float* p = hop + (size_t)j * DHID + t * 8;
    float4 a = *(const float4*)p;
    float4 b = *(const float4*)(p + 4);
    float s = a.x + a.y + a.z + a.w + b.x + b.y + b.z + b.w;
#pragma unroll
    for (int m = 1; m < 64; m <<= 1) s += __shfl_xor(s, m);
    if (t == 0) hm[j] = s * (1.0f / (float)DHID);
}

// ---------------------------------------------------------------------------
// BT MFMA GEMM: C[M,N] = A[M,K] * Bt[N,K]^T + epilogue  (A,Bt,C bf16)
// Tile 128x128x32, 256 threads (4 waves as 2x2 of 64x64), 16x16x32 MFMA.
// EPI_QKV: N=1536 concat [Q|K|Vt]; sel = gn>>9 is block-uniform.
// ---------------------------------------------------------------------------
enum { EPI_BIAS = 0, EPI_RELU = 1, EPI_PLAIN = 3, EPI_BIAS_T = 4, EPI_QKV = 5 };

template <int EPI>
__global__ __launch_bounds__(256) void gemm_bt(
    const u16* __restrict__ A, const u16* __restrict__ Bt, u16* __restrict__ C,
    const float* __restrict__ bias,
    int K, int lda, int ldb, int ldc,
    u16* __restrict__ Qo, u16* __restrict__ Ko, u16* __restrict__ Vto,
    const float* __restrict__ bq_, const float* __restrict__ bk_,
    const float* __restrict__ bv_)
{
    __shared__ u16 As[128 * 32];   // 8 KB, [row][k], row stride 64 B
    __shared__ u16 Bs[128 * 32];   // 8 KB, [n][k]

    const int tid = threadIdx.x;
    const u16* Ab = A;
    const u16* Bb = Bt;

    const int bm0 = blockIdx.y * 128, bn0 = blockIdx.x * 128;
    const int wid = tid >> 6, lane = tid & 63, quad = lane >> 4, l16 = lane & 15;
    const int wm = (wid >> 1) * 64, wn = (wid & 1) * 64;
    const int srow = lane >> 2;            // 0..15: row within 16-row chunk
    const int skof = (lane & 3) * 8;       // k element offset (8 bf16 = 16 B)

    f32x4 acc[4][4];
#pragma unroll
    for (int i = 0; i < 4; ++i)
#pragma unroll
        for (int j = 0; j < 4; ++j) acc[i][j] = (f32x4){0.f, 0.f, 0.f, 0.f};

    for (int k0 = 0; k0 < K; k0 += 32) {
#pragma unroll
        for (int it = 0; it < 2; ++it) {
            int c = wid * 2 + it;          // wave-uniform
            gld_lds16(Ab + (size_t)(bm0 + c * 16 + srow) * lda + k0 + skof,
                      &As[c * 512]);
        }
#pragma unroll
        for (int it = 0; it < 2; ++it) {
            int c = wid * 2 + it;
            gld_lds16(Bb + (size_t)(bn0 + c * 16 + srow) * ldb + k0 + skof,
                      &Bs[c * 512]);
        }
        __syncthreads();

        bf16x8 af[4], bfr[4];
#pragma unroll
        for (int i = 0; i < 4; ++i)
            af[i] = *(const bf16x8*)&As[(wm + i * 16 + l16) * 32 + quad * 8];
#pragma unroll
        for (int j = 0; j < 4; ++j)
            bfr[j] = *(const bf16x8*)&Bs[(wn + j * 16 + l16) * 32 + quad * 8];
#pragma unroll
        for (int i = 0; i < 4; ++i)
#pragma unroll
            for (int j = 0; j < 4; ++j)
                acc[i][j] = __builtin_amdgcn_mfma_f32_16x16x32_bf16(af[i], bfr[j], acc[i][j], 0, 0, 0);
        __syncthreads();
    }

    // ---- epilogue: C/D layout col=lane&15, row=quad*4+reg ----
#pragma unroll
    for (int i = 0; i < 4; ++i) {
#pragma unroll
        for (int j = 0; j < 4; ++j) {
            const int gn = bn0 + wn + j * 16 + l16;
            const int gm0 = bm0 + wm + i * 16 + quad * 4;
            if constexpr (EPI == EPI_BIAS || EPI == EPI_RELU) {
                const float b = bias[gn];
#pragma unroll
                for (int r = 0; r < 4; ++r) {
                    float v = acc[i][j][r] + b;
                    if constexpr (EPI == EPI_RELU) v = fmaxf(v, 0.f);
                    C[(size_t)(gm0 + r) * ldc + gn] = f2bf(v);
                }
            } else if constexpr (EPI == EPI_BIAS_T) {
                const float b = bias[gn];
                const int bb = gm0 >> 11, n = gm0 & 2047;
                ushort4 o;
                o.x = f2bf(acc[i][j][0] + b);
                o.y = f2bf(acc[i][j][1] + b);
                o.z = f2bf(acc[i][j][2] + b);
                o.w = f2bf(acc[i][j][3] + b);
                *(ushort4*)&C[((size_t)bb * 512 + gn) * 2048 + n] = o;
            } else if constexpr (EPI == EPI_QKV) {
                const int sel = gn >> 9;     // block-uniform (bn0 128-aligned)
                const int n = gn & 511;
                if (sel == 0) {
                    const float b = bq_[n];
#pragma unroll
                    for (int r = 0; r < 4; ++r)
                        Qo[(size_t)(gm0 + r) * DHID + n] = f2bf(acc[i][j][r] + b);
                } else if (sel == 1) {
                    const float b = bk_[n];
#pragma unroll
                    for (int r = 0; r < 4; ++r)
                        Ko[(size_t)(gm0 + r) * DHID + n] = f2bf(acc[i][j][r] + b);
                } else {
                    const float b = bv_[n];
                    const int bb = gm0 >> 11, nn2 = gm0 & 2047;
                    ushort4 o;
                    o.x = f2bf(acc[i][j][0] + b);
                    o.y = f2bf(acc[i][j][1] + b);
                    o.z = f2bf(acc[i][j][2] + b);
                    o.w = f2bf(acc[i][j][3] + b);
                    *(ushort4*)&Vto[((size_t)bb * 512 + n) * 2048 + nn2] = o;
                }
            } else {
#pragma unroll
                for (int r = 0; r < 4; ++r)
                    C[(size_t)(gm0 + r) * ldc + gn] = f2bf(acc[i][j][r]);
            }
        }
    }
}

// ---------------------------------------------------------------------------
// Fused attention v8: block = (batch bx, 32 Q-rows by). 4 waves:
// wave w -> rows (w>>1)*16; kv-half (QK^T) and d-half (PV) = w&1.
//
// v3..v7 post-mortem: the kernel is LDS-READ-PIPE bound (~49 ds_read_b128 per
// wave-iter x 12cy x 8 waves + 1570cy conflicts ~= the whole 7760cy iter);
// scheduling changes were neutral. v8 cuts reads 33% by eliminating the
// DUPLICATED QK^T: previously d-half wave pairs computed identical S[16x32].
// Now each wave computes only its kv-half S[16x16] (16 MFMA, 16 K reads) and
// the pair shares P through LDS:
//   B1 (__syncthreads): drains K[kt] stage (issued last iter, covered by
//       softmax+PV); orders prev PV reads before Vs restage.
//   stage Vs[kt]; load adj/hm scalars (wave's 16 cols only).
//   QK^T: 16 MFMA on Ks[.][ch].
//   B2 (__syncthreads): drains Vs (v5 lesson: each wave drains own vmcnt at
//       the barrier -> all waves' gld_lds data visible after it).
//   issue Ks[kt+1] stage (latency covered by softmax+PV+next B1).
//   softmax: 4 exp; write P columns ch*16..+16 into pair-shared Pg.
//   B3 (lgkm drain + raw s_barrier): P is plain ds_write -> per-wave lgkm
//       drain + barrier makes it visible; K gld_lds stays in flight (vmcnt
//       NOT drained here).
//   PV: pf = full P row frag (32 kv); 16 MFMA vs Vs d-half.
// lsum: each wave accumulates only its kv-half; combined once at the end
// via a small LDS exchange (SUMS aliases Pb).
// LDS 68096B: Ks 32KB | Vs 32KB | Pb 2.5KB -> 2 blocks/CU.
// ---------------------------------------------------------------------------
__global__ __launch_bounds__(256, 2) void attn_kernel(
    const u16* __restrict__ Q, const u16* __restrict__ K, const u16* __restrict__ Vt,
    const float* __restrict__ adj, const float* __restrict__ hm,
    u16* __restrict__ AO)
{
    extern __shared__ u16 lds[];                 // 68096 B
    u16* Ks = lds;                               // [ds16][c2][16 rows x 32 u16]
    u16* Vs = lds + 16384;                       // [d512][kv32]
    u16* Pb = lds + 32768;                       // 2 row-groups x 640 u16

    const int tid = threadIdx.x, wid = tid >> 6, lane = tid & 63;
    const int quad = lane >> 4, l16 = lane & 15;
    const int b = blockIdx.x;                    // batch -> XCD affinity
    const int q0 = blockIdx.y * 32 + (wid >> 1) * 16;  // wave's 16 Q-rows
    const int ch = wid & 1;                      // kv-half (QK^T) / d-half (PV)
    const int D0 = ch * 256;
    const int srow = lane >> 2, sko = (lane & 3) * 8;

    const u16* Qg = Q + (size_t)b * SEQN * DHID;
    const u16* Kg = K + (size_t)b * SEQN * DHID;
    const u16* Vg = Vt + (size_t)b * DHID * SEQN;
    const float* adjg = adj + (size_t)b * SEQN * SEQN;
    u16* AOg = AO + (size_t)b * SEQN * DHID;
    const float* arow = adjg + (size_t)(q0 + quad * 4) * SEQN;
    u16* Pg = Pb + (wid >> 1) * 640;             // shared by the d-half pair

    const float scale = 0.044194173824159216f;   // 1/sqrt(512)

    // Q fragments (A-layout): lane holds Q[q0+l16][ds*32+quad*8+j]
    bf16x8 qf[16];
#pragma unroll
    for (int ds = 0; ds < 16; ++ds)
        qf[ds] = *(const bf16x8*)(Qg + (size_t)(q0 + l16) * DHID + ds * 32 + quad * 8);

    f32x4 oacc[16];
#pragma unroll
    for (int dt = 0; dt < 16; ++dt) oacc[dt] = (f32x4){0.f, 0.f, 0.f, 0.f};
    float lsum[4] = {0.f, 0.f, 0.f, 0.f};

    // ---- prologue: issue Ks = K[0] staging; drained by first B1 ----
#pragma unroll
    for (int i = 0; i < 8; ++i) {
        int id = wid * 8 + i, ds = id >> 1, c = id & 1;
        gld_lds16(Kg + (size_t)(c * 16 + srow) * DHID + ds * 32 + sko,
                  &Ks[ds * 1024 + c * 512]);
    }

    for (int kt = 0; kt < 64; ++kt) {
        const int kv0 = kt * 32;

        // [B1] drains own vmcnt (K[kt] stage) + lgkm (prev PV/pf reads), barrier.
        __syncthreads();

        // ---- stage Vs[kt] async (drained at B2, covered by QK^T) ----
#pragma unroll
        for (int i = 0; i < 8; ++i) {
            int id = wid * 8 + i;                // d-rows id*16..id*16+16
            gld_lds16(Vg + (size_t)(id * 16 + srow) * SEQN + kv0 + sko,
                      &Vs[id * 512]);
        }

        // ---- scalar loads for the wave's 16 kv-cols (used post-B2) ----
        float hv = hm[kv0 + ch * 16 + l16] * scale;
        float av[4];
#pragma unroll
        for (int r = 0; r < 4; ++r)
            av[r] = arow[(size_t)r * SEQN + kv0 + ch * 16 + l16];

        // ---- QK^T: S 16x16 (wave's kv-half), 2 chains, reads Ks[.][ch] ----
        f32x4 sa = {0.f,0.f,0.f,0.f}, sb = {0.f,0.f,0.f,0.f};
#pragma unroll
        for (int ds = 0; ds < 16; ds += 2) {
            bf16x8 k0 = *(const bf16x8*)&Ks[ds * 1024 + ch * 512 + l16 * 32 + quad * 8];
            sa = __builtin_amdgcn_mfma_f32_16x16x32_bf16(qf[ds], k0, sa, 0, 0, 0);
            bf16x8 k1 = *(const bf16x8*)&Ks[(ds + 1) * 1024 + ch * 512 + l16 * 32 + quad * 8];
            sb = __builtin_amdgcn_mfma_f32_16x16x32_bf16(qf[ds + 1], k1, sb, 0, 0, 0);
        }
        f32x4 s = sa + sb;

        // [B2] drains own vmcnt (Vs + scalars) + lgkm (Ks reads), barrier.
        __syncthreads();

        // ---- stage Ks[kt+1] NOW (drained at next B1; softmax+PV cover) ----
        if (kt < 63) {
#pragma unroll
            for (int i = 0; i < 8; ++i) {
                int id = wid * 8 + i, ds = id >> 1, c = id & 1;
                gld_lds16(Kg + (size_t)(kv0 + 32 + c * 16 + srow) * DHID + ds * 32 + sko,
                          &Ks[ds * 1024 + c * 512]);
            }
        }
        __builtin_amdgcn_sched_barrier(0);       // keep K issue above softmax/PV

        // ---- softmax: 4 exp, write wave's P columns into shared Pg ----
#pragma unroll
        for (int r = 0; r < 4; ++r) {
            float p = __expf(s[r] * av[r] * hv);
            lsum[r] += p;                         // wave's kv-half partial sum
            Pg[(quad * 4 + r) * 40 + ch * 16 + l16] = f2bf(p);
        }

        // [B3] P complete across the pair: own lgkm drain + raw barrier.
        // (P is plain ds_write -> visible after barrier; K gld_lds vmcnt
        //  intentionally NOT drained here.)
        asm volatile("s_waitcnt lgkmcnt(0)" ::: "memory");
        __builtin_amdgcn_s_barrier();
        __builtin_amdgcn_sched_barrier(0);

        bf16x8 pf = *(const bf16x8*)&Pg[l16 * 40 + quad * 8];

        // ---- PV: O[16 x 256] += P[16x32] @ V[32 x d-half] ----
#pragma unroll
        for (int dt = 0; dt < 16; ++dt) {
            bf16x8 vf = *(const bf16x8*)&Vs[(D0 + dt * 16 + l16) * 32 + quad * 8];
            oacc[dt] = __builtin_amdgcn_mfma_f32_16x16x32_bf16(pf, vf, oacc[dt], 0, 0, 0);
        }
    }

    // ---- finalize: reduce kv-half sums over l16 group, combine across the
    //      d-half pair via LDS, normalize, store ----
#pragma unroll
    for (int r = 0; r < 4; ++r) {
#pragma unroll
        for (int m = 1; m < 16; m <<= 1) lsum[r] += __shfl_xor(lsum[r], m);
    }
    __syncthreads();                             // last PV/pf reads done
    float* SUMS = (float*)Pb;                    // [4 waves][16 rows]
    if (l16 == 0) {
#pragma unroll
        for (int r = 0; r < 4; ++r) SUMS[wid * 16 + quad * 4 + r] = lsum[r];
    }
    __syncthreads();
#pragma unroll
    for (int r = 0; r < 4; ++r)
        lsum[r] = 1.f / (lsum[r] + SUMS[(wid ^ 1) * 16 + quad * 4 + r]);

#pragma unroll
    for (int dt = 0; dt < 16; ++dt) {
#pragma unroll
        for (int r = 0; r < 4; ++r) {
            AOg[(size_t)(q0 + quad * 4 + r) * DHID + D0 + dt * 16 + l16] =
                f2bf(oacc[dt][r] * lsum[r]);
        }
    }
}

// ---------------------------------------------------------------------------
// LN1: x = LN(a + Hf) * g + be   (a bf16, Hf fp32, out bf16)
// ---------------------------------------------------------------------------
__global__ __launch_bounds__(256) void ln_hf32_kernel(
    const u16* __restrict__ a, const float* __restrict__ Hf,
    const float* __restrict__ g, const float* __restrict__ be,
    u16* __restrict__ out)
{
    size_t row = blockIdx.x;
    int t = threadIdx.x, wid = t >> 6, lane = t & 63;
    unsigned int va = *(const unsigned int*)(a + row * (size_t)DHID + t * 2);
    float2 h = *(const float2*)(Hf + row * (size_t)DHID + t * 2);
    float x0 = bf2f((u16)(va & 0xffff)) + h.x;
    float x1 = bf2f((u16)(va >> 16)) + h.y;
    float s = x0 + x1, sq = x0 * x0 + x1 * x1;
#pragma unroll
    for (int m = 1; m < 64; m <<= 1) { s += __shfl_xor(s, m); sq += __shfl_xor(sq, m); }
    __shared__ float rs[4], rq[4];
    if (lane == 0) { rs[wid] = s; rq[wid] = sq; }
    __syncthreads();
    s = rs[0] + rs[1] + rs[2] + rs[3];
    sq = rq[0] + rq[1] + rq[2] + rq[3];
    float mean = s * (1.f / (float)DHID);
    float var = sq * (1.f / (float)DHID) - mean * mean;
    float rstd = rsqrtf(var + 1e-5f);
    float2 vg = *(const float2*)(g + t * 2);
    float2 vbe = *(const float2*)(be + t * 2);
    float y0 = (x0 - mean) * rstd * vg.x + vbe.x;
    float y1 = (x1 - mean) * rstd * vg.y + vbe.y;
    unsigned int o = (unsigned int)f2bf(y0) | ((unsigned int)f2bf(y1) << 16);
    *(unsigned int*)(out + row * (size_t)DHID + t * 2) = o;
}

// ---------------------------------------------------------------------------
// LN2: out = LN(a + b) * g + be   (a,b bf16, out fp32)
// ---------------------------------------------------------------------------
__global__ __launch_bounds__(256) void ln_kernel_f32out(
    const u16* __restrict__ a, const u16* __restrict__ bp,
    const float* __restrict__ g, const float* __restrict__ be,
    float* __restrict__ out)
{
    size_t row = blockIdx.x;
    int t = threadIdx.x, wid = t >> 6, lane = t & 63;
    unsigned int va = *(const unsigned int*)(a + row * (size_t)DHID + t * 2);
    unsigned int vb = *(const unsigned int*)(bp + row * (size_t)DHID + t * 2);
    float x0 = bf2f((u16)(va & 0xffff)) + bf2f((u16)(vb & 0xffff));
    float x1 = bf2f((u16)(va >> 16)) + bf2f((u16)(vb >> 16));
    float s = x0 + x1, sq = x0 * x0 + x1 * x1;
#pragma unroll
    for (int m = 1; m < 64; m <<= 1) { s += __shfl_xor(s, m); sq += __shfl_xor(sq, m); }
    __shared__ float rs[4], rq[4];
    if (lane == 0) { rs[wid] = s; rq[wid] = sq; }
    __syncthreads();
    s = rs[0] + rs[1] + rs[2] + rs[3];
    sq = rq[0] + rq[1] + rq[2] + rq[3];
    float mean = s * (1.f / (float)DHID);
    float var = sq * (1.f / (float)DHID) - mean * mean;
    float rstd = rsqrtf(var + 1e-5f);
    float2 vg = *(const float2*)(g + t * 2);
    float2 vbe = *(const float2*)(be + t * 2);
    float y0 = (x0 - mean) * rstd * vg.x + vbe.x;
    float y1 = (x1 - mean) * rstd * vg.y + vbe.y;
    *(float2*)(out + row * (size_t)DHID + t * 2) = make_float2(y0, y1);
}

// ---------------------------------------------------------------------------
extern "C" void kernel_launch(void* const* d_in, const int* in_sizes, int n_in,
                              void* d_out, int out_size, void* d_ws, size_t ws_size,
                              hipStream_t stream) {
    const float* H   = (const float*)d_in[0];
    const float* adj = (const float*)d_in[1];
    const float* hop = (const float*)d_in[2];
    const float* Wq  = (const float*)d_in[3];
    const float* bq  = (const float*)d_in[4];
    const float* Wk  = (const float*)d_in[5];
    const float* bk  = (const float*)d_in[6];
    const float* Wv  = (const float*)d_in[7];
    const float* bv  = (const float*)d_in[8];
    const float* W1  = (const float*)d_in[9];
    const float* b1  = (const float*)d_in[10];
    const float* W2  = (const float*)d_in[11];
    const float* b2  = (const float*)d_in[12];
    const float* g1  = (const float*)d_in[13];
    const float* be1 = (const float*)d_in[14];
    const float* g2  = (const float*)d_in[15];
    const float* be2 = (const float*)d_in[16];

    const size_t MiB = 1ull << 20;
    char* w = (char*)d_ws;
    float* hm   = (float*)w;                      // 8 KB
    u16* Hb    = (u16*)(w + 1 * MiB);             // 16 MiB
    u16* Wqkvt = (u16*)(w + 17 * MiB);            // 1.5 MiB [Wq^T|Wk^T|Wv^T]
    u16* W1t   = (u16*)(w + 18 * MiB + 512 * 1024); // 1 MiB
    u16* W2t   = (u16*)(w + 19 * MiB + 512 * 1024); // 1 MiB
    u16* Q     = (u16*)(w + 21 * MiB);            // 16 MiB
    u16* Kb    = (u16*)(w + 37 * MiB);            // 16 MiB
    u16* Vt    = (u16*)(w + 53 * MiB);            // 16 MiB  [b][512][2048]
    u16* AO    = (u16*)(w + 69 * MiB);            // 16 MiB
    u16* HID   = (u16*)(w + 85 * MiB);            // 32 MiB -> total 117 MiB
    // aliases (lifetimes disjoint):
    u16* X   = Kb;   // LN1 output (K dead after attention)
    u16* F2  = Vt;   // ffn2 output (V dead after attention)

    const int BN = 8, N = SEQN, D = DHID;

    // fp32 -> bf16 conversions (weights transposed, QKV concatenated)
    cvt_kernel<<<(BN * N * D) / (8 * 256), 256, 0, stream>>>(H, Hb, BN * N * D);
    cvt_t_kernel<<<(D * D + 255) / 256, 256, 0, stream>>>(Wq, Wqkvt, D, D);
    cvt_t_kernel<<<(D * D + 255) / 256, 256, 0, stream>>>(Wk, Wqkvt + D * D, D, D);
    cvt_t_kernel<<<(D * D + 255) / 256, 256, 0, stream>>>(Wv, Wqkvt + 2 * D * D, D, D);
    cvt_t_kernel<<<(D * 2 * D + 255) / 256, 256, 0, stream>>>(W1, W1t, D, 2 * D);
    cvt_t_kernel<<<(2 * D * D + 255) / 256, 256, 0, stream>>>(W2, W2t, 2 * D, D);

    hmean_kernel<<<N, 64, 0, stream>>>(hop, hm);

    // fused QKV: C[16384,1536] over [Q|K|Vt] outputs
    gemm_bt<EPI_QKV><<<dim3(12, 128, 1), 256, 0, stream>>>(
        Hb, Wqkvt, nullptr, nullptr, D, D, D, 0, Q, Kb, Vt, bq, bk, bv);

    // fused attention: 512 blocks (8 batches x 64 stripes of 32 rows), 2/CU
    attn_kernel<<<dim3(8, 64), 256, 68096, stream>>>(Q, Kb, Vt, adj, hm, AO);

    // x = LN(attn_out + H)
    ln_hf32_kernel<<<BN * N, 256, 0, stream>>>(AO, H, g1, be1, X);

    // hid = relu(x @ W1 + b1)
    gemm_bt<EPI_RELU><<<dim3(8, 128, 1), 256, 0, stream>>>(
        X, W1t, HID, b1, D, D, D, 2 * D, nullptr, nullptr, nullptr, nullptr, nullptr, nullptr);

    // f2 = hid @ W2 + b2
    gemm_bt<EPI_BIAS><<<dim3(4, 128, 1), 256, 0, stream>>>(
        HID, W2t, F2, b2, 2 * D, 2 * D, 2 * D, D, nullptr, nullptr, nullptr, nullptr, nullptr, nullptr);

    // out = LN(f2 + x)  -> fp32 d_out
    ln_kernel_f32out<<<BN * N, 256, 0, stream>>>(F2, X, g2, be2, (float*)d_out);
}